// Round 2
// baseline (335.207 us; speedup 1.0000x reference)
//
#include <hip/hip_runtime.h>

// ---------------------------------------------------------------------------
// FCGF_point_att2_ican_fc: per-point score -> global BN(1) -> per-segment
// softmax attention pooling -> FC(32,64) -> BN(64).
//
// N = 1,048,576 points x 32 feats (128 MiB fp32), B = 64 segments.
// Two passes over x are structural (softmax weights need global z-stats).
//
// R5: last-block tickets. R4 showed the kernels are no longer the dominant
// cost (top-5 dispatches are all 512-MiB harness poison fills at 86% HBM
// peak); the controllable part is ~50 us. Remaining fat: k_pool's per-block
// dpart re-reduction (2048 x 32 KB = 64 MB L3 + latency prelude in every
// block) and the separate k_head launch. Now: k_stats's last block (device
// atomic ticket) reduces dpart once -> consts; k_pool's last block runs the
// head. 2 kernels + one 16-B memset (tickets must be re-zeroed because the
// harness re-poisons the workspace every iteration).
// ---------------------------------------------------------------------------

#define EPS 1e-5f
#define NSB 2048          // blocks in k_stats
#define CHUNKS 32         // k_pool chunks per segment -> 2048 blocks

// workspace layout (bytes)
#define WS_CNT     0          // int cnt0, cnt1 (memset to 0 each launch)
#define WS_DPART   16         // double[2*NSB] = 32768 B
#define WS_CONSTS  32784      // float c1, c2
#define WS_OFFS    32800      // int[65] segment offsets
#define WS_GNUM    33064      // float[64*32] sum(e*x)
#define WS_GDEN    41256      // float[64]    sum(e)

// ---------------------------------------------------------------------------
// Pass 1: octet (8 lanes) owns a row; lane l&7 loads float4 q of the row ->
// fully coalesced. Dot(w1) reduced over the octet with shfl_xor 1,2,4;
// q==0 lane accumulates (z, z^2) in double. Block 0 zeroes gnum/gden and
// prefix-scans lengths -> offs. The LAST block to finish (ticket) reduces
// the 2048 double partials -> c1 = g1*rsqrt(var+eps), c2 = beta1 - c1*mu.
__global__ __launch_bounds__(256, 8) void k_stats(const float* __restrict__ x,
                                                  const float* __restrict__ w1,
                                                  const float* __restrict__ b1,
                                                  const float* __restrict__ g1,
                                                  const float* __restrict__ beta1,
                                                  const int* __restrict__ length,
                                                  int N, int B,
                                                  int* __restrict__ cnt,
                                                  double* __restrict__ dpart,
                                                  float* __restrict__ consts,
                                                  int* __restrict__ offs,
                                                  float* __restrict__ gnum,
                                                  float* __restrict__ gden) {
    const int tid = threadIdx.x;

    if (blockIdx.x == 0) {
        for (int i = tid; i < B * 32; i += 256) gnum[i] = 0.f;
        for (int i = tid; i < B; i += 256) gden[i] = 0.f;
        __shared__ int slen[256];
        for (int i = tid; i < B; i += 256) slen[i] = length[i];
        __syncthreads();
        if (tid == 0) {
            int o = 0;
            offs[0] = 0;
            for (int bb = 0; bb < B; ++bb) { o += slen[bb]; offs[bb + 1] = o; }
        }
    }

    const int q = tid & 7;
    const float4 wq = ((const float4*)w1)[q];
    const float b1v = b1[0];
    const float4* __restrict__ xv = (const float4*)x;

    double accZ = 0.0, accZZ = 0.0;
    const int stride = gridDim.x * 32;              // rows per grid iteration
    for (int row = blockIdx.x * 32 + (tid >> 3); row < N; row += stride) {
        float4 v = xv[(size_t)row * 8 + q];
        float zp = v.x * wq.x;
        zp = fmaf(v.y, wq.y, zp);
        zp = fmaf(v.z, wq.z, zp);
        zp = fmaf(v.w, wq.w, zp);
        zp += __shfl_xor(zp, 1);
        zp += __shfl_xor(zp, 2);
        zp += __shfl_xor(zp, 4);                    // all 8 lanes hold full dot
        if (q == 0) {
            double z = (double)(zp + b1v);
            accZ  += z;
            accZZ += z * z;
        }
    }

    __shared__ double sZ[256], sZZ[256];
    sZ[tid] = accZ; sZZ[tid] = accZZ;
    __syncthreads();
    for (int s = 128; s > 0; s >>= 1) {
        if (tid < s) { sZ[tid] += sZ[tid + s]; sZZ[tid] += sZZ[tid + s]; }
        __syncthreads();
    }

    __shared__ int isLast;
    if (tid == 0) {
        dpart[2 * blockIdx.x]     = sZ[0];
        dpart[2 * blockIdx.x + 1] = sZZ[0];
        __threadfence();                             // release: dpart visible
        isLast = (atomicAdd(cnt, 1) == (int)gridDim.x - 1);
    }
    __syncthreads();

    if (isLast) {
        __threadfence();                             // acquire: see all dpart
        double aZ = 0.0, aZZ = 0.0;
        const double2* __restrict__ dp2 = (const double2*)dpart;
        for (int i = tid; i < NSB; i += 256) {
            double2 d = dp2[i];
            aZ += d.x; aZZ += d.y;
        }
        sZ[tid] = aZ; sZZ[tid] = aZZ;
        __syncthreads();
        for (int s = 128; s > 0; s >>= 1) {
            if (tid < s) { sZ[tid] += sZ[tid + s]; sZZ[tid] += sZZ[tid + s]; }
            __syncthreads();
        }
        if (tid == 0) {
            double mu  = sZ[0] / (double)N;
            double var = sZZ[0] / (double)N - mu * mu;
            float c1 = (float)((double)g1[0] / sqrt(var + (double)EPS));
            consts[0] = c1;
            consts[1] = beta1[0] - (float)(c1 * mu);
        }
    }
}

// ---------------------------------------------------------------------------
// Pass 2: s = (c1*z + c2) * rowmean; e = exp(s) (segment-max skipped:
// |s| <~ 3, exactly equivalent after normalization). Coalesced octet layout;
// acc is one float4/lane = its 4 columns. Grid: (CHUNKS, seg). The LAST
// block to finish (ticket) runs the head: pooled = num/(den*len);
// h = pooled @ W2 + b2; BN over B rows -> out.
__global__ __launch_bounds__(256, 4) void k_pool(const float* __restrict__ x,
                                                 const float* __restrict__ w1,
                                                 const float* __restrict__ b1,
                                                 const float* __restrict__ consts,
                                                 const int* __restrict__ offs,
                                                 const int* __restrict__ length,
                                                 const float* __restrict__ W2,
                                                 const float* __restrict__ b2,
                                                 const float* __restrict__ g2,
                                                 const float* __restrict__ beta2,
                                                 int* __restrict__ cnt,
                                                 float* __restrict__ gnum,
                                                 float* __restrict__ gden,
                                                 float* __restrict__ out,
                                                 int B) {
    const int tid = threadIdx.x;
    const float c1 = consts[0], c2 = consts[1];

    const int b   = blockIdx.y;
    const int off = offs[b];
    const int len = offs[b + 1] - off;
    const int rpc = (len + CHUNKS - 1) / CHUNKS;
    const int r0  = blockIdx.x * rpc;
    const int r1  = min(r0 + rpc, len);

    const int q = tid & 7;
    const float4 wq = ((const float4*)w1)[q];
    const float b1v = b1[0];
    const float4* __restrict__ xv = (const float4*)x;

    float4 acc = make_float4(0.f, 0.f, 0.f, 0.f);
    float accE = 0.f;

    for (int r = r0 + (tid >> 3); r < r1; r += 32) {
        float4 v = xv[(size_t)(off + r) * 8 + q];
        float zp = v.x * wq.x;
        zp = fmaf(v.y, wq.y, zp);
        zp = fmaf(v.z, wq.z, zp);
        zp = fmaf(v.w, wq.w, zp);
        float mp = v.x + v.y + v.z + v.w;
        zp += __shfl_xor(zp, 1);  mp += __shfl_xor(mp, 1);
        zp += __shfl_xor(zp, 2);  mp += __shfl_xor(mp, 2);
        zp += __shfl_xor(zp, 4);  mp += __shfl_xor(mp, 4);
        float s = fmaf(c1, zp + b1v, c2) * mp * 0.03125f;
        float e = __expf(s);
        acc.x = fmaf(e, v.x, acc.x);
        acc.y = fmaf(e, v.y, acc.y);
        acc.z = fmaf(e, v.z, acc.z);
        acc.w = fmaf(e, v.w, acc.w);
        if (q == 0) accE += e;
    }

    // cross-octet butterfly: lanes with same q sum over the wave's rows
#pragma unroll
    for (int msk = 8; msk < 64; msk <<= 1) {
        acc.x += __shfl_xor(acc.x, msk);
        acc.y += __shfl_xor(acc.y, msk);
        acc.z += __shfl_xor(acc.z, msk);
        acc.w += __shfl_xor(acc.w, msk);
        accE  += __shfl_xor(accE,  msk);
    }

    // LDS: sred overlays the head scratch (separated by __syncthreads below)
    __shared__ float shead[64 * 32 + 64 * 64 + 128];   // pooled | h | mu2 isd
    float* sred = shead;                               // [4][33] view
    const int wave = tid >> 6;
    const int lane = tid & 63;
    if (lane < 8) {
        sred[wave * 33 + 4 * lane + 0] = acc.x;
        sred[wave * 33 + 4 * lane + 1] = acc.y;
        sred[wave * 33 + 4 * lane + 2] = acc.z;
        sred[wave * 33 + 4 * lane + 3] = acc.w;
        if (lane == 0) sred[wave * 33 + 32] = accE;
    }
    __syncthreads();
    if (tid < 33) {
        float s = sred[0 * 33 + tid] + sred[1 * 33 + tid] +
                  sred[2 * 33 + tid] + sred[3 * 33 + tid];
        if (tid < 32) atomicAdd(&gnum[b * 32 + tid], s);
        else          atomicAdd(&gden[b], s);
        __threadfence();                               // release: atomics visible
    }
    __syncthreads();

    __shared__ int isLast;
    if (tid == 0)
        isLast = (atomicAdd(cnt, 1) == (int)(gridDim.x * gridDim.y) - 1);
    __syncthreads();
    if (!isLast) return;

    // ---- head (single block) ----
    __threadfence();                                   // acquire: see gnum/gden
    float* pooled = shead;                             // [64*32]
    float* h      = shead + 64 * 32;                   // [64*64]
    float* mu2    = shead + 64 * 32 + 64 * 64;         // [64]
    float* isd    = mu2 + 64;                          // [64]

    for (int i = tid; i < B * 32; i += 256) {
        int bb = i >> 5;
        pooled[i] = gnum[i] / (gden[bb] * (float)length[bb]);
    }
    __syncthreads();

    const int j = tid & 63;       // output feature
    const int g = tid >> 6;       // 0..3 row group
    for (int r = 0; r < 16; ++r) {
        int bb = g * 16 + r;
        if (bb < B) {
            float hv = b2[j];
            for (int k = 0; k < 32; ++k) hv += pooled[bb * 32 + k] * W2[k * 64 + j];
            h[bb * 64 + j] = hv;
        }
    }
    __syncthreads();

    if (tid < 64) {
        float m = 0.f;
        for (int bb = 0; bb < B; ++bb) m += h[bb * 64 + tid];
        m /= (float)B;
        float v = 0.f;
        for (int bb = 0; bb < B; ++bb) { float d = h[bb * 64 + tid] - m; v += d * d; }
        v /= (float)B;
        mu2[tid] = m;
        isd[tid] = rsqrtf(v + EPS);
    }
    __syncthreads();

    for (int r = 0; r < 16; ++r) {
        int bb = g * 16 + r;
        if (bb < B) {
            int idx = bb * 64 + j;
            out[idx] = g2[j] * (h[idx] - mu2[j]) * isd[j] + beta2[j];
        }
    }
}

// ---------------------------------------------------------------------------
extern "C" void kernel_launch(void* const* d_in, const int* in_sizes, int n_in,
                              void* d_out, int out_size, void* d_ws, size_t ws_size,
                              hipStream_t stream) {
    const float* x      = (const float*)d_in[0];
    const int*   length = (const int*)  d_in[1];
    const float* w1     = (const float*)d_in[2];
    const float* b1     = (const float*)d_in[3];
    const float* g1     = (const float*)d_in[4];
    const float* beta1  = (const float*)d_in[5];
    const float* W2     = (const float*)d_in[6];
    const float* b2     = (const float*)d_in[7];
    const float* g2     = (const float*)d_in[8];
    const float* beta2  = (const float*)d_in[9];
    float* out = (float*)d_out;

    const int N = in_sizes[0] / 32;
    const int B = in_sizes[1];

    char* ws = (char*)d_ws;
    int*    cnt    = (int*)   (ws + WS_CNT);     // cnt[0]=k_stats, cnt[1]=k_pool
    double* dpart  = (double*)(ws + WS_DPART);
    float*  consts = (float*) (ws + WS_CONSTS);
    int*    offs   = (int*)   (ws + WS_OFFS);
    float*  gnum   = (float*) (ws + WS_GNUM);
    float*  gden   = (float*) (ws + WS_GDEN);

    // tickets must be re-zeroed every iteration (ws is re-poisoned by harness)
    hipMemsetAsync(cnt, 0, 16, stream);

    k_stats<<<NSB, 256, 0, stream>>>(x, w1, b1, g1, beta1, length, N, B,
                                     cnt + 0, dpart, consts, offs, gnum, gden);
    k_pool <<<dim3(CHUNKS, B), 256, 0, stream>>>(x, w1, b1, consts, offs, length,
                                                 W2, b2, g2, beta2, cnt + 1,
                                                 gnum, gden, out, B);
}

// Round 3
// 245.112 us; speedup vs baseline: 1.3676x; 1.3676x over previous
//
#include <hip/hip_runtime.h>

// ---------------------------------------------------------------------------
// FCGF_point_att2_ican_fc: per-point score -> global BN(1) -> per-segment
// softmax attention pooling -> FC(32,64) -> BN(64).
//
// N = 1,048,576 points x 32 feats (128 MiB fp32), B = 64 segments.
// Two passes over x are structural (softmax weights need global z-stats);
// the second pass reads x L3-resident (128 MiB < 256 MiB Infinity Cache).
//
// R6: revert R5's last-block tickets. R5's per-block __threadfence()
// (device-scope release = L2 writeback on gfx950) + atomicAdd ticket made
// the byte-identical k_stats loop 4-5x slower (110 us, VALUBusy 4%,
// 0.6 TB/s = stall-bound, measured). Fence-free R4 structure restored:
// 3 stream-ordered kernels, k_pool re-reduces dpart per block
// (deterministic, off the serial path). NSB 2048->1024 halves that
// prelude. No memsets, no fences, no tickets.
// ---------------------------------------------------------------------------

#define EPS 1e-5f
#define NSB 1024          // blocks in k_stats (4/CU)
#define CHUNKS 32         // k_pool chunks per segment -> 2048 blocks

// workspace layout (bytes)
#define WS_DPART   0          // double[2*NSB] = 16384 B
#define WS_OFFS    16384      // int[65] segment offsets
#define WS_GNUM    16896      // float[64*32] sum(e*x)
#define WS_GDEN    25088      // float[64]    sum(e)

// ---------------------------------------------------------------------------
// Pass 1: octet (8 lanes) owns a row; lane l&7 loads float4 q of the row ->
// addresses are base + lane*16, fully coalesced. Dot(w1) reduced over the
// octet with shfl_xor 1,2,4; q==0 lane accumulates (z, z^2) in double.
// Block 0 additionally zeroes gnum/gden and prefix-scans lengths -> offs.
__global__ __launch_bounds__(256, 8) void k_stats(const float* __restrict__ x,
                                                  const float* __restrict__ w1,
                                                  const float* __restrict__ b1,
                                                  const int* __restrict__ length,
                                                  int N, int B,
                                                  double* __restrict__ dpart,
                                                  int* __restrict__ offs,
                                                  float* __restrict__ gnum,
                                                  float* __restrict__ gden) {
    const int tid = threadIdx.x;

    if (blockIdx.x == 0) {
        for (int i = tid; i < B * 32; i += 256) gnum[i] = 0.f;
        for (int i = tid; i < B; i += 256) gden[i] = 0.f;
        __shared__ int slen[256];
        for (int i = tid; i < B; i += 256) slen[i] = length[i];
        __syncthreads();
        if (tid == 0) {
            int o = 0;
            offs[0] = 0;
            for (int bb = 0; bb < B; ++bb) { o += slen[bb]; offs[bb + 1] = o; }
        }
    }

    const int q = tid & 7;
    const float4 wq = ((const float4*)w1)[q];
    const float b1v = b1[0];
    const float4* __restrict__ xv = (const float4*)x;

    double accZ = 0.0, accZZ = 0.0;
    const int stride = gridDim.x * 32;              // rows per grid iteration
    for (int row = blockIdx.x * 32 + (tid >> 3); row < N; row += stride) {
        float4 v = xv[(size_t)row * 8 + q];
        float zp = v.x * wq.x;
        zp = fmaf(v.y, wq.y, zp);
        zp = fmaf(v.z, wq.z, zp);
        zp = fmaf(v.w, wq.w, zp);
        zp += __shfl_xor(zp, 1);
        zp += __shfl_xor(zp, 2);
        zp += __shfl_xor(zp, 4);                    // all 8 lanes hold full dot
        if (q == 0) {
            double z = (double)(zp + b1v);
            accZ  += z;
            accZZ += z * z;
        }
    }

    __shared__ double sZ[256], sZZ[256];
    sZ[tid] = accZ; sZZ[tid] = accZZ;
    __syncthreads();
    for (int s = 128; s > 0; s >>= 1) {
        if (tid < s) { sZ[tid] += sZ[tid + s]; sZZ[tid] += sZZ[tid + s]; }
        __syncthreads();
    }
    if (tid == 0) {
        dpart[2 * blockIdx.x]     = sZ[0];
        dpart[2 * blockIdx.x + 1] = sZZ[0];
    }
}

// ---------------------------------------------------------------------------
// Pass 2: each block first re-reduces dpart -> c1,c2 (deterministic,
// identical in every block; 16 KB from L2, off the serial path — measured
// cheaper than any cross-block handoff). Then pooled pass, coalesced octet
// layout; e = exp(s) (segment-max skipped: |s| <~ 3, exactly equivalent
// after normalization). acc is one float4/lane = its 4 columns.
// Grid: (CHUNKS, seg) — each block entirely inside one segment.
__global__ __launch_bounds__(256, 8) void k_pool(const float* __restrict__ x,
                                                 const float* __restrict__ w1,
                                                 const float* __restrict__ b1,
                                                 const float* __restrict__ g1,
                                                 const float* __restrict__ beta1,
                                                 const double* __restrict__ dpart,
                                                 const int* __restrict__ offs,
                                                 int N,
                                                 float* __restrict__ gnum,
                                                 float* __restrict__ gden) {
    const int tid = threadIdx.x;

    // --- per-block reduction of double partials -> c1, c2 ---
    __shared__ double sZ[256], sZZ[256];
    double aZ = 0.0, aZZ = 0.0;
    const double2* __restrict__ dp2 = (const double2*)dpart;
    for (int i = tid; i < NSB; i += 256) {
        double2 d = dp2[i];
        aZ += d.x; aZZ += d.y;
    }
    sZ[tid] = aZ; sZZ[tid] = aZZ;
    __syncthreads();
    for (int s = 128; s > 0; s >>= 1) {
        if (tid < s) { sZ[tid] += sZ[tid + s]; sZZ[tid] += sZZ[tid + s]; }
        __syncthreads();
    }
    __shared__ float cb[2];
    if (tid == 0) {
        double mu  = sZ[0] / (double)N;
        double var = sZZ[0] / (double)N - mu * mu;
        float c1 = (float)((double)g1[0] / sqrt(var + (double)EPS));
        cb[0] = c1;
        cb[1] = beta1[0] - (float)(c1 * mu);
    }
    __syncthreads();
    const float c1 = cb[0], c2 = cb[1];

    // --- pooled pass ---
    const int b   = blockIdx.y;
    const int off = offs[b];
    const int len = offs[b + 1] - off;
    const int rpc = (len + CHUNKS - 1) / CHUNKS;
    const int r0  = blockIdx.x * rpc;
    const int r1  = min(r0 + rpc, len);

    const int q = tid & 7;
    const float4 wq = ((const float4*)w1)[q];
    const float b1v = b1[0];
    const float4* __restrict__ xv = (const float4*)x;

    float4 acc = make_float4(0.f, 0.f, 0.f, 0.f);
    float accE = 0.f;

    for (int r = r0 + (tid >> 3); r < r1; r += 32) {
        float4 v = xv[(size_t)(off + r) * 8 + q];
        float zp = v.x * wq.x;
        zp = fmaf(v.y, wq.y, zp);
        zp = fmaf(v.z, wq.z, zp);
        zp = fmaf(v.w, wq.w, zp);
        float mp = v.x + v.y + v.z + v.w;
        zp += __shfl_xor(zp, 1);  mp += __shfl_xor(mp, 1);
        zp += __shfl_xor(zp, 2);  mp += __shfl_xor(mp, 2);
        zp += __shfl_xor(zp, 4);  mp += __shfl_xor(mp, 4);
        float s = fmaf(c1, zp + b1v, c2) * mp * 0.03125f;
        float e = __expf(s);
        acc.x = fmaf(e, v.x, acc.x);
        acc.y = fmaf(e, v.y, acc.y);
        acc.z = fmaf(e, v.z, acc.z);
        acc.w = fmaf(e, v.w, acc.w);
        if (q == 0) accE += e;
    }

    // cross-octet butterfly: lanes with same q sum over the wave's rows
#pragma unroll
    for (int msk = 8; msk < 64; msk <<= 1) {
        acc.x += __shfl_xor(acc.x, msk);
        acc.y += __shfl_xor(acc.y, msk);
        acc.z += __shfl_xor(acc.z, msk);
        acc.w += __shfl_xor(acc.w, msk);
        accE  += __shfl_xor(accE,  msk);
    }

    // lanes 0..7 of each wave hold columns q*4..q*4+3; lane 0 holds accE
    __shared__ float sred[4][33];
    const int wave = tid >> 6;
    const int lane = tid & 63;
    if (lane < 8) {
        sred[wave][4 * lane + 0] = acc.x;
        sred[wave][4 * lane + 1] = acc.y;
        sred[wave][4 * lane + 2] = acc.z;
        sred[wave][4 * lane + 3] = acc.w;
        if (lane == 0) sred[wave][32] = accE;
    }
    __syncthreads();
    if (tid < 33) {
        float s = sred[0][tid] + sred[1][tid] + sred[2][tid] + sred[3][tid];
        if (tid < 32) atomicAdd(&gnum[b * 32 + tid], s);
        else          atomicAdd(&gden[b], s);
    }
}

// ---------------------------------------------------------------------------
// Epilogue: pooled = num/(den*len); h = pooled @ W2 + b2; BN over B rows.
__global__ __launch_bounds__(256) void k_head(const float* __restrict__ gnum,
                                              const float* __restrict__ gden,
                                              const int* __restrict__ length,
                                              const float* __restrict__ W2,
                                              const float* __restrict__ b2,
                                              const float* __restrict__ g2,
                                              const float* __restrict__ beta2,
                                              float* __restrict__ out, int B) {
    __shared__ float pooled[64 * 32];
    __shared__ float h[64 * 64];
    __shared__ float mu2[64], isd[64];
    const int tid = threadIdx.x;

    for (int i = tid; i < B * 32; i += 256) {
        int bb = i >> 5;
        pooled[i] = gnum[i] / (gden[bb] * (float)length[bb]);
    }
    __syncthreads();

    const int j = tid & 63;       // output feature
    const int g = tid >> 6;       // 0..3 row group
    for (int r = 0; r < 16; ++r) {
        int bb = g * 16 + r;
        if (bb < B) {
            float hv = b2[j];
            for (int k = 0; k < 32; ++k) hv += pooled[bb * 32 + k] * W2[k * 64 + j];
            h[bb * 64 + j] = hv;
        }
    }
    __syncthreads();

    if (tid < 64) {
        float m = 0.f;
        for (int bb = 0; bb < B; ++bb) m += h[bb * 64 + tid];
        m /= (float)B;
        float v = 0.f;
        for (int bb = 0; bb < B; ++bb) { float d = h[bb * 64 + tid] - m; v += d * d; }
        v /= (float)B;
        mu2[tid] = m;
        isd[tid] = rsqrtf(v + EPS);
    }
    __syncthreads();

    for (int r = 0; r < 16; ++r) {
        int bb = g * 16 + r;
        if (bb < B) {
            int idx = bb * 64 + j;
            out[idx] = g2[j] * (h[idx] - mu2[j]) * isd[j] + beta2[j];
        }
    }
}

// ---------------------------------------------------------------------------
extern "C" void kernel_launch(void* const* d_in, const int* in_sizes, int n_in,
                              void* d_out, int out_size, void* d_ws, size_t ws_size,
                              hipStream_t stream) {
    const float* x      = (const float*)d_in[0];
    const int*   length = (const int*)  d_in[1];
    const float* w1     = (const float*)d_in[2];
    const float* b1     = (const float*)d_in[3];
    const float* g1     = (const float*)d_in[4];
    const float* beta1  = (const float*)d_in[5];
    const float* W2     = (const float*)d_in[6];
    const float* b2     = (const float*)d_in[7];
    const float* g2     = (const float*)d_in[8];
    const float* beta2  = (const float*)d_in[9];
    float* out = (float*)d_out;

    const int N = in_sizes[0] / 32;
    const int B = in_sizes[1];

    char* ws = (char*)d_ws;
    double* dpart  = (double*)(ws + WS_DPART);
    int*    offs   = (int*)   (ws + WS_OFFS);
    float*  gnum   = (float*) (ws + WS_GNUM);
    float*  gden   = (float*) (ws + WS_GDEN);

    k_stats<<<NSB, 256, 0, stream>>>(x, w1, b1, length, N, B, dpart, offs, gnum, gden);
    k_pool <<<dim3(CHUNKS, B), 256, 0, stream>>>(x, w1, b1, g1, beta1, dpart, offs, N,
                                                 gnum, gden);
    k_head <<<1, 256, 0, stream>>>(gnum, gden, length, W2, b2, g2, beta2, out, B);
}